// Round 11
// baseline (255.323 us; speedup 1.0000x reference)
//
#include <hip/hip_runtime.h>

#define NN 50000
#define NE 1600000
#define ET (NE + NN)          // edges + self loops
#define NEG 0.2f
#define NBUCK 196             // ceil(50000/256): bucket = dst >> 8
#define CAP 10240             // per-bucket capacity (mean 8418, ~20 sigma margin)
#define NBLK_A ((ET + 4095) / 4096)       // 403
#define G1_BLOCKS ((NN + 31) / 32)        // 1563
#define G1_SPLIT 782                       // gemm1 rows [0,25024) in K1, rest in K2

typedef unsigned int uint;

__device__ __forceinline__ float bflo(uint u){ return __uint_as_float(u << 16); }
__device__ __forceinline__ float bfhi(uint u){ return __uint_as_float(u & 0xffff0000u); }
__device__ __forceinline__ uint f2bf2(float lo, float hi){
    uint a = __float_as_uint(lo); a += 0x7fffu + ((a >> 16) & 1u);
    uint b = __float_as_uint(hi); b += 0x7fffu + ((b >> 16) & 1u);
    return (a >> 16) | (b & 0xffff0000u);
}
__device__ __forceinline__ int clampn(int v){ return v < 0 ? 0 : (v >= NN ? NN - 1 : v); }

__device__ __forceinline__ int load_src(const int* ei, int i64, int t){
    return clampn(i64 ? ei[2 * t] : ei[t]);
}
__device__ __forceinline__ int load_dst(const int* ei, int i64, int t){
    return clampn(i64 ? ei[2 * NE + 2 * t] : ei[NE + t]);
}

// ---------------- CSR phase A body (coarse bucket by dst>>8), self-detecting dtype ----------------
__device__ __forceinline__ void bucketA_body(char* smem, int b, const int* __restrict__ ei,
                                             int* __restrict__ gcur, uint* __restrict__ bdata){
    int* hist = (int*)smem;
    int* base = hist + NBUCK;
    int t = threadIdx.x;
    // per-block dtype detect: if int64 little-endian (values < 50000), every odd int32 is 0.
    // 256 samples of random node-ids being all-zero for int32 data: p ~ (2e-5)^256 ~ 0.
    hist[t] = ei[2 * (t * 6250) + 1];
    __syncthreads();
    for (int o = 128; o > 0; o >>= 1){
        if (t < o) hist[t] |= hist[t + o];
        __syncthreads();
    }
    int i64 = (hist[0] == 0) ? 1 : 0;
    __syncthreads();
    for (int j = t; j < NBUCK; j += 256) hist[j] = 0;
    __syncthreads();
    int e0 = b * 4096;
    int sarr[16], darr[16];
    if (e0 + 4096 <= NE){
        int eb = e0 + t * 16;
        if (i64){
            const int4* s4 = (const int4*)ei + (eb >> 1);
            const int4* d4 = (const int4*)(ei + 2 * NE) + (eb >> 1);
            #pragma unroll
            for (int q = 0; q < 8; ++q){
                int4 v = s4[q]; sarr[2*q] = v.x; sarr[2*q+1] = v.z;
                int4 w = d4[q]; darr[2*q] = w.x; darr[2*q+1] = w.z;
            }
        } else {
            const int4* s4 = (const int4*)ei + (eb >> 2);
            const int4* d4 = (const int4*)(ei + NE) + (eb >> 2);
            #pragma unroll
            for (int q = 0; q < 4; ++q){
                int4 v = s4[q]; sarr[4*q]=v.x; sarr[4*q+1]=v.y; sarr[4*q+2]=v.z; sarr[4*q+3]=v.w;
                int4 w = d4[q]; darr[4*q]=w.x; darr[4*q+1]=w.y; darr[4*q+2]=w.z; darr[4*q+3]=w.w;
            }
        }
        #pragma unroll
        for (int j = 0; j < 16; ++j){ sarr[j] = clampn(sarr[j]); darr[j] = clampn(darr[j]); }
    } else {
        #pragma unroll
        for (int j = 0; j < 16; ++j){
            int e = e0 + t * 16 + j;
            if (e < NE){ sarr[j] = load_src(ei, i64, e); darr[j] = load_dst(ei, i64, e); }
            else if (e < ET){ sarr[j] = e - NE; darr[j] = e - NE; }
            else { sarr[j] = -1; darr[j] = -1; }
        }
    }
    uint vals[16]; int bks[16];
    #pragma unroll
    for (int j = 0; j < 16; ++j){
        if (darr[j] >= 0){
            int bk = darr[j] >> 8;
            bks[j] = bk;
            vals[j] = ((uint)(darr[j] & 255) << 17) | (uint)sarr[j];
            atomicAdd(&hist[bk], 1);
        } else bks[j] = -1;
    }
    __syncthreads();
    for (int j = t; j < NBUCK; j += 256){
        int c = hist[j];
        base[j] = c ? atomicAdd(&gcur[j], c) : 0;
        hist[j] = 0;
    }
    __syncthreads();
    #pragma unroll
    for (int j = 0; j < 16; ++j){
        int bk = bks[j];
        if (bk >= 0){
            int lp = base[bk] + atomicAdd(&hist[bk], 1);
            if (lp < CAP) bdata[(size_t)bk * CAP + lp] = vals[j];
        }
    }
}

// ---------------- CSR phase B body (scan folded in; uint4 reads; count+scan+scatter) ----------------
__device__ __forceinline__ void bucketB_body(char* smem, int b, const uint* __restrict__ bdata,
                                             const int* __restrict__ gcur, int* __restrict__ offsets,
                                             int* __restrict__ ends, int* __restrict__ csr){
    int* hist = (int*)smem;
    int* excl = hist + 256;
    int* sgb  = excl + 256;
    int t = threadIdx.x;
    int cv = (t < NBUCK) ? gcur[t] : 0; if (cv > CAP) cv = CAP;
    excl[t] = cv;
    __syncthreads();
    for (int o = 1; o < 256; o <<= 1){
        int x = (t >= o) ? excl[t - o] : 0;
        __syncthreads();
        excl[t] += x;
        __syncthreads();
    }
    if (t == b) *sgb = excl[t] - cv;
    __syncthreads();
    int gb = *sgb;
    int n = gcur[b]; if (n > CAP) n = CAP;
    hist[t] = 0;
    __syncthreads();
    const uint* bd = bdata + (size_t)b * CAP;
    const uint4* bd4 = (const uint4*)bd;
    int n4 = n >> 2;
    for (int i = t; i < n4; i += 256){
        uint4 v = bd4[i];
        atomicAdd(&hist[v.x >> 17], 1);
        atomicAdd(&hist[v.y >> 17], 1);
        atomicAdd(&hist[v.z >> 17], 1);
        atomicAdd(&hist[v.w >> 17], 1);
    }
    for (int i = 4 * n4 + t; i < n; i += 256)
        atomicAdd(&hist[bd[i] >> 17], 1);
    __syncthreads();
    int v = hist[t];
    excl[t] = v;
    __syncthreads();
    for (int o = 1; o < 256; o <<= 1){
        int x = (t >= o) ? excl[t - o] : 0;
        __syncthreads();
        excl[t] += x;
        __syncthreads();
    }
    int ex = excl[t] - v;
    int node = b * 256 + t;
    if (node < NN){ offsets[node] = gb + ex; ends[node] = gb + ex + v; }
    __syncthreads();
    hist[t] = ex;              // reuse as local cursor
    __syncthreads();
    for (int i = t; i < n4; i += 256){
        uint4 w = bd4[i];
        int lp;
        lp = atomicAdd(&hist[w.x >> 17], 1); csr[gb + lp] = (int)(w.x & 0x1FFFFu);
        lp = atomicAdd(&hist[w.y >> 17], 1); csr[gb + lp] = (int)(w.y & 0x1FFFFu);
        lp = atomicAdd(&hist[w.z >> 17], 1); csr[gb + lp] = (int)(w.z & 0x1FFFFu);
        lp = atomicAdd(&hist[w.w >> 17], 1); csr[gb + lp] = (int)(w.w & 0x1FFFFu);
    }
    for (int i = 4 * n4 + t; i < n; i += 256){
        uint val = bd[i];
        int lp = atomicAdd(&hist[val >> 17], 1);
        csr[gb + lp] = (int)(val & 0x1FFFFu);
    }
}

// ---------------- GEMM1 body (+ fused al1): h1 = x @ W1, bf16-packed out ----------------
// W1 from global (coalesced 512 B spans, L1-resident); only x rows in LDS (16 KB).
__device__ __forceinline__ void gemm1_body(char* smem, int gb, const float* __restrict__ x,
                                           const float* __restrict__ W1, const float* __restrict__ as1,
                                           const float* __restrict__ ad1, uint* __restrict__ h1b,
                                           float* __restrict__ als, float* __restrict__ ald){
    float* xs = (float*)smem;             // 32x128 = 16 KB
    int t = threadIdx.x;
    int row0 = gb * 32;
    const float4* x4 = (const float4*)x;
    float4* xs4 = (float4*)xs;
    #pragma unroll
    for (int j = 0; j < 4; ++j){
        int idx = t + j * 256;
        int gi = row0 * 32 + idx;
        if (gi < NN * 32) xs4[idx] = x4[gi];
    }
    __syncthreads();
    int rg = t >> 5, cg = t & 31;
    float acc[4][4];
    #pragma unroll
    for (int i = 0; i < 4; ++i)
        #pragma unroll
        for (int c = 0; c < 4; ++c) acc[i][c] = 0.f;
    const float4* W4 = (const float4*)W1;   // [k][cg] float4
    for (int k4 = 0; k4 < 32; ++k4){
        int k = k4 * 4;
        float4 xv[4];
        #pragma unroll
        for (int i = 0; i < 4; ++i) xv[i] = xs4[(rg * 4 + i) * 32 + k4];
        float4 w0 = W4[(k + 0) * 32 + cg];
        float4 w1 = W4[(k + 1) * 32 + cg];
        float4 w2 = W4[(k + 2) * 32 + cg];
        float4 w3 = W4[(k + 3) * 32 + cg];
        #pragma unroll
        for (int i = 0; i < 4; ++i){
            acc[i][0] = fmaf(xv[i].x, w0.x, acc[i][0]);
            acc[i][1] = fmaf(xv[i].x, w0.y, acc[i][1]);
            acc[i][2] = fmaf(xv[i].x, w0.z, acc[i][2]);
            acc[i][3] = fmaf(xv[i].x, w0.w, acc[i][3]);
            acc[i][0] = fmaf(xv[i].y, w1.x, acc[i][0]);
            acc[i][1] = fmaf(xv[i].y, w1.y, acc[i][1]);
            acc[i][2] = fmaf(xv[i].y, w1.z, acc[i][2]);
            acc[i][3] = fmaf(xv[i].y, w1.w, acc[i][3]);
            acc[i][0] = fmaf(xv[i].z, w2.x, acc[i][0]);
            acc[i][1] = fmaf(xv[i].z, w2.y, acc[i][1]);
            acc[i][2] = fmaf(xv[i].z, w2.z, acc[i][2]);
            acc[i][3] = fmaf(xv[i].z, w2.w, acc[i][3]);
            acc[i][0] = fmaf(xv[i].w, w3.x, acc[i][0]);
            acc[i][1] = fmaf(xv[i].w, w3.y, acc[i][1]);
            acc[i][2] = fmaf(xv[i].w, w3.z, acc[i][2]);
            acc[i][3] = fmaf(xv[i].w, w3.w, acc[i][3]);
        }
    }
    int h = cg >> 3, c0 = (cg & 7) * 4;
    const float* ash = as1 + h * 32 + c0;
    const float* adh = ad1 + h * 32 + c0;
    float as0 = ash[0], as1v = ash[1], as2v = ash[2], as3v = ash[3];
    float ad0 = adh[0], ad1v = adh[1], ad2v = adh[2], ad3v = adh[3];
    #pragma unroll
    for (int i = 0; i < 4; ++i){
        int n = row0 + rg * 4 + i;
        if (n < NN){
            ((uint2*)h1b)[n * 32 + cg] = make_uint2(f2bf2(acc[i][0], acc[i][1]),
                                                    f2bf2(acc[i][2], acc[i][3]));
            float ps = acc[i][0] * as0 + acc[i][1] * as1v + acc[i][2] * as2v + acc[i][3] * as3v;
            float pd = acc[i][0] * ad0 + acc[i][1] * ad1v + acc[i][2] * ad2v + acc[i][3] * ad3v;
            ps += __shfl_xor(ps, 1); pd += __shfl_xor(pd, 1);
            ps += __shfl_xor(ps, 2); pd += __shfl_xor(pd, 2);
            ps += __shfl_xor(ps, 4); pd += __shfl_xor(pd, 4);
            if ((cg & 7) == 0){ als[n * 4 + h] = ps; ald[n * 4 + h] = pd; }
        }
    }
}

// ---------------- K1: bucketA (blocks 0..402) + gemm1 rows [0,25024) ----------------
__global__ __launch_bounds__(256) void k1_kernel(const int* __restrict__ ei,
                                                 int* __restrict__ gcur, uint* __restrict__ bdata,
                                                 const float* __restrict__ x, const float* __restrict__ W1,
                                                 const float* __restrict__ as1, const float* __restrict__ ad1,
                                                 uint* __restrict__ h1b, float* __restrict__ als,
                                                 float* __restrict__ ald){
    __shared__ __align__(16) char smem[32 * 128 * 4];   // 16 KB
    if ((int)blockIdx.x < NBLK_A) bucketA_body(smem, blockIdx.x, ei, gcur, bdata);
    else gemm1_body(smem, blockIdx.x - NBLK_A, x, W1, as1, ad1, h1b, als, ald);
}

// ---------------- K2: bucketB (blocks 0..195) + gemm1 rows [25024,50000) ----------------
__global__ __launch_bounds__(256) void k2_kernel(const uint* __restrict__ bdata, const int* __restrict__ gcur,
                                                 int* __restrict__ offsets, int* __restrict__ ends,
                                                 int* __restrict__ csr,
                                                 const float* __restrict__ x, const float* __restrict__ W1,
                                                 const float* __restrict__ as1, const float* __restrict__ ad1,
                                                 uint* __restrict__ h1b, float* __restrict__ als,
                                                 float* __restrict__ ald){
    __shared__ __align__(16) char smem[32 * 128 * 4];   // 16 KB
    if ((int)blockIdx.x < NBUCK) bucketB_body(smem, blockIdx.x, bdata, gcur, offsets, ends, csr);
    else gemm1_body(smem, blockIdx.x - NBUCK + G1_SPLIT, x, W1, as1, ad1, h1b, als, ald);
}

// ---------------- edge1: wave per node, quartet uint4 gathers, no max pass ----------------
__global__ __launch_bounds__(256) void edge1_kernel(const int* __restrict__ offs, const int* __restrict__ ends,
                                                    const int* __restrict__ csr, const uint* __restrict__ h1b,
                                                    const float* __restrict__ als, const float* __restrict__ ald,
                                                    const float* __restrict__ b1, uint* __restrict__ helub){
    __shared__ int   ss[4][64];
    __shared__ float sw[4][64][4];
    int t = threadIdx.x, wave = t >> 6, lane = t & 63;
    int node = blockIdx.x * 4 + wave;     // grid exact: NN/4
    int begin = offs[node], end = ends[node];
    int deg = end - begin;
    int eg = lane >> 4, cl = lane & 15, hh = cl >> 2;
    float4 ad = ((const float4*)ald)[node];
    const float4* als4 = (const float4*)als;
    const uint4* h1b4 = (const uint4*)h1b;

    float ws0 = 0, ws1 = 0, ws2 = 0, ws3 = 0;
    float acc[8];
    #pragma unroll
    for (int i = 0; i < 8; ++i) acc[i] = 0.f;
    bool fast = (deg <= 64);

    if (fast){
        float w0 = 0, w1 = 0, w2 = 0, w3 = 0;
        int s0 = 0;
        if (lane < deg){
            s0 = csr[begin + lane];
            float4 a = als4[s0];
            float e0 = a.x + ad.x; e0 = e0 > 0.f ? e0 : NEG * e0; w0 = __expf(e0);
            float e1 = a.y + ad.y; e1 = e1 > 0.f ? e1 : NEG * e1; w1 = __expf(e1);
            float e2 = a.z + ad.z; e2 = e2 > 0.f ? e2 : NEG * e2; w2 = __expf(e2);
            float e3 = a.w + ad.w; e3 = e3 > 0.f ? e3 : NEG * e3; w3 = __expf(e3);
            ws0 = w0; ws1 = w1; ws2 = w2; ws3 = w3;
        }
        ss[wave][lane] = s0;
        sw[wave][lane][0] = w0; sw[wave][lane][1] = w1;
        sw[wave][lane][2] = w2; sw[wave][lane][3] = w3;
        __threadfence_block();
        int dlim = (deg + 3) & ~3;       // zero-weight padding makes tails safe
        int j = 0;
        for (; j + 16 <= dlim; j += 16){
            int sj[4]; float wj[4]; uint4 v[4];
            #pragma unroll
            for (int q = 0; q < 4; ++q){
                sj[q] = ss[wave][j + 4 * q + eg];
                wj[q] = sw[wave][j + 4 * q + eg][hh];
            }
            #pragma unroll
            for (int q = 0; q < 4; ++q) v[q] = h1b4[(size_t)sj[q] * 16 + cl];
            #pragma unroll
            for (int q = 0; q < 4; ++q){
                acc[0] = fmaf(wj[q], bflo(v[q].x), acc[0]);
                acc[1] = fmaf(wj[q], bfhi(v[q].x), acc[1]);
                acc[2] = fmaf(wj[q], bflo(v[q].y), acc[2]);
                acc[3] = fmaf(wj[q], bfhi(v[q].y), acc[3]);
                acc[4] = fmaf(wj[q], bflo(v[q].z), acc[4]);
                acc[5] = fmaf(wj[q], bfhi(v[q].z), acc[5]);
                acc[6] = fmaf(wj[q], bflo(v[q].w), acc[6]);
                acc[7] = fmaf(wj[q], bfhi(v[q].w), acc[7]);
            }
        }
        for (; j < dlim; j += 4){
            int sj = ss[wave][j + eg]; float wj = sw[wave][j + eg][hh];
            uint4 v = h1b4[(size_t)sj * 16 + cl];
            acc[0] = fmaf(wj, bflo(v.x), acc[0]);
            acc[1] = fmaf(wj, bfhi(v.x), acc[1]);
            acc[2] = fmaf(wj, bflo(v.y), acc[2]);
            acc[3] = fmaf(wj, bfhi(v.y), acc[3]);
            acc[4] = fmaf(wj, bflo(v.z), acc[4]);
            acc[5] = fmaf(wj, bfhi(v.z), acc[5]);
            acc[6] = fmaf(wj, bflo(v.w), acc[6]);
            acc[7] = fmaf(wj, bfhi(v.w), acc[7]);
        }
    } else {
        for (int base = begin; base < end; base += 64){
            int n = end - base; if (n > 64) n = 64;
            float w0 = 0, w1 = 0, w2 = 0, w3 = 0; int sv = 0;
            if (lane < n){
                sv = csr[base + lane];
                float4 a = als4[sv];
                float f0 = a.x + ad.x; f0 = f0 > 0.f ? f0 : NEG * f0; w0 = __expf(f0);
                float f1 = a.y + ad.y; f1 = f1 > 0.f ? f1 : NEG * f1; w1 = __expf(f1);
                float f2 = a.z + ad.z; f2 = f2 > 0.f ? f2 : NEG * f2; w2 = __expf(f2);
                float f3 = a.w + ad.w; f3 = f3 > 0.f ? f3 : NEG * f3; w3 = __expf(f3);
                ws0 += w0; ws1 += w1; ws2 += w2; ws3 += w3;
            }
            __threadfence_block();
            ss[wave][lane] = sv;
            sw[wave][lane][0] = w0; sw[wave][lane][1] = w1;
            sw[wave][lane][2] = w2; sw[wave][lane][3] = w3;
            __threadfence_block();
            int dlim = (n + 3) & ~3;
            for (int j = 0; j < dlim; j += 4){
                int sj = ss[wave][j + eg]; float wj = sw[wave][j + eg][hh];
                uint4 v = h1b4[(size_t)sj * 16 + cl];
                acc[0] = fmaf(wj, bflo(v.x), acc[0]);
                acc[1] = fmaf(wj, bfhi(v.x), acc[1]);
                acc[2] = fmaf(wj, bflo(v.y), acc[2]);
                acc[3] = fmaf(wj, bfhi(v.y), acc[3]);
                acc[4] = fmaf(wj, bflo(v.z), acc[4]);
                acc[5] = fmaf(wj, bfhi(v.z), acc[5]);
                acc[6] = fmaf(wj, bflo(v.w), acc[6]);
                acc[7] = fmaf(wj, bfhi(v.w), acc[7]);
            }
        }
    }
    for (int o = 32; o > 0; o >>= 1){
        ws0 += __shfl_xor(ws0, o); ws1 += __shfl_xor(ws1, o);
        ws2 += __shfl_xor(ws2, o); ws3 += __shfl_xor(ws3, o);
    }
    #pragma unroll
    for (int i = 0; i < 8; ++i){
        acc[i] += __shfl_xor(acc[i], 16);
        acc[i] += __shfl_xor(acc[i], 32);
    }
    if (eg == 0){
        float wsum = hh == 0 ? ws0 : (hh == 1 ? ws1 : (hh == 2 ? ws2 : ws3));
        float inv = 1.f / (wsum + 1e-16f);
        int c0 = cl * 8;
        float o[8];
        #pragma unroll
        for (int i = 0; i < 8; ++i){
            float v = acc[i] * inv + b1[c0 + i];
            o[i] = v > 0.f ? v : __expf(v) - 1.f;   // ELU
        }
        uint4 pk = make_uint4(f2bf2(o[0], o[1]), f2bf2(o[2], o[3]),
                              f2bf2(o[4], o[5]), f2bf2(o[6], o[7]));
        ((uint4*)helub)[(size_t)node * 16 + cl] = pk;
    }
}

// ---------------- GEMM2 (+ fused al2): h2 = helu @ W2, bf16-packed out ----------------
// W2 read from global (32 KB = L1-sized, each quarter-wave reads the same 256 B span);
// LDS holds only the padded helu tile -> LDS reads halved, occupancy up.
__global__ __launch_bounds__(256) void gemm2_kernel(const uint* __restrict__ helub, const float* __restrict__ W2,
                                                    const float* __restrict__ as2, const float* __restrict__ ad2,
                                                    uint* __restrict__ h2b, float* __restrict__ als2,
                                                    float* __restrict__ ald2){
    __shared__ uint hsu[64 * 65];    // ~16.6 KB, row-major padded
    int t = threadIdx.x;
    int row0 = blockIdx.x * 64;
    const uint4* hb4 = (const uint4*)helub;
    #pragma unroll
    for (int j = 0; j < 4; ++j){
        int idx = t + j * 256;
        int gi = row0 * 16 + idx;
        if (gi < NN * 16){
            uint4 v = hb4[gi];
            int r = idx >> 4, kq = idx & 15;
            uint* dst = hsu + r * 65 + kq * 4;
            dst[0] = v.x; dst[1] = v.y; dst[2] = v.z; dst[3] = v.w;
        }
    }
    __syncthreads();
    int rg = t >> 4, cg = t & 15;
    float acc[4][4];
    #pragma unroll
    for (int i = 0; i < 4; ++i)
        #pragma unroll
        for (int c = 0; c < 4; ++c) acc[i][c] = 0.f;
    const float4* W24 = (const float4*)W2;   // [k][cg] float4, row = 64 floats = 16 float4
    for (int k2 = 0; k2 < 64; ++k2){
        uint hv[4];
        #pragma unroll
        for (int i = 0; i < 4; ++i) hv[i] = hsu[(rg * 4 + i) * 65 + k2];
        float4 wa = W24[(2 * k2) * 16 + cg];
        float4 wb = W24[(2 * k2 + 1) * 16 + cg];
        #pragma unroll
        for (int i = 0; i < 4; ++i){
            float xl = bflo(hv[i]), xh = bfhi(hv[i]);
            acc[i][0] = fmaf(xl, wa.x, acc[i][0]);
            acc[i][1] = fmaf(xl, wa.y, acc[i][1]);
            acc[i][2] = fmaf(xl, wa.z, acc[i][2]);
            acc[i][3] = fmaf(xl, wa.w, acc[i][3]);
            acc[i][0] = fmaf(xh, wb.x, acc[i][0]);
            acc[i][1] = fmaf(xh, wb.y, acc[i][1]);
            acc[i][2] = fmaf(xh, wb.z, acc[i][2]);
            acc[i][3] = fmaf(xh, wb.w, acc[i][3]);
        }
    }
    int c0 = cg * 4;
    float s0 = as2[c0], s1 = as2[c0 + 1], s2 = as2[c0 + 2], s3 = as2[c0 + 3];
    float d0 = ad2[c0], d1 = ad2[c0 + 1], d2 = ad2[c0 + 2], d3 = ad2[c0 + 3];
    #pragma unroll
    for (int i = 0; i < 4; ++i){
        int n = row0 + rg * 4 + i;
        if (n < NN){
            ((uint2*)h2b)[n * 16 + cg] = make_uint2(f2bf2(acc[i][0], acc[i][1]),
                                                    f2bf2(acc[i][2], acc[i][3]));
            float ps = acc[i][0] * s0 + acc[i][1] * s1 + acc[i][2] * s2 + acc[i][3] * s3;
            float pd = acc[i][0] * d0 + acc[i][1] * d1 + acc[i][2] * d2 + acc[i][3] * d3;
            ps += __shfl_xor(ps, 1); pd += __shfl_xor(pd, 1);
            ps += __shfl_xor(ps, 2); pd += __shfl_xor(pd, 2);
            ps += __shfl_xor(ps, 4); pd += __shfl_xor(pd, 4);
            ps += __shfl_xor(ps, 8); pd += __shfl_xor(pd, 8);
            if (cg == 0){ als2[n] = ps; ald2[n] = pd; }
        }
    }
}

// ---------------- edge2: wave per node, octet uint4 gathers (16 B/lane), no max pass ----------------
__global__ __launch_bounds__(256) void edge2_kernel(const int* __restrict__ offs, const int* __restrict__ ends,
                                                    const int* __restrict__ csr, const uint* __restrict__ h2b,
                                                    const float* __restrict__ als, const float* __restrict__ ald,
                                                    const float* __restrict__ b2, float* __restrict__ out){
    __shared__ int   ss2[4][64];
    __shared__ float sw2[4][64];
    int t = threadIdx.x, wave = t >> 6, lane = t & 63;
    int node = blockIdx.x * 4 + wave;     // grid exact: NN/4
    int begin = offs[node], end = ends[node];
    int deg = end - begin;
    int eg = lane >> 3, cl = lane & 7;    // edge-in-octet, uint4-chunk
    float adv = ald[node];
    const uint4* h2p4 = (const uint4*)h2b;  // row = 8 uint4 (64 bf16 ch)
    float wsl = 0.f;
    float acc[8] = {0.f, 0.f, 0.f, 0.f, 0.f, 0.f, 0.f, 0.f};
    bool fast = (deg <= 64);
    if (fast){
        float w = 0.f; int sv = 0;
        if (lane < deg){
            sv = csr[begin + lane];
            float e = als[sv] + adv; e = e > 0.f ? e : NEG * e;
            w = __expf(e); wsl = w;
        }
        ss2[wave][lane] = sv;
        sw2[wave][lane] = w;
        __threadfence_block();
        int dlim = (deg + 7) & ~7;        // zero-weight padding
        int j = 0;
        for (; j + 16 <= dlim; j += 16){
            int sj0 = ss2[wave][j + eg],     sj1 = ss2[wave][j + 8 + eg];
            float wj0 = sw2[wave][j + eg],   wj1 = sw2[wave][j + 8 + eg];
            uint4 v0 = h2p4[(size_t)sj0 * 8 + cl];
            uint4 v1 = h2p4[(size_t)sj1 * 8 + cl];
            acc[0] = fmaf(wj0, bflo(v0.x), acc[0]); acc[1] = fmaf(wj0, bfhi(v0.x), acc[1]);
            acc[2] = fmaf(wj0, bflo(v0.y), acc[2]); acc[3] = fmaf(wj0, bfhi(v0.y), acc[3]);
            acc[4] = fmaf(wj0, bflo(v0.z), acc[4]); acc[5] = fmaf(wj0, bfhi(v0.z), acc[5]);
            acc[6] = fmaf(wj0, bflo(v0.w), acc[6]); acc[7] = fmaf(wj0, bfhi(v0.w), acc[7]);
            acc[0] = fmaf(wj1, bflo(v1.x), acc[0]); acc[1] = fmaf(wj1, bfhi(v1.x), acc[1]);
            acc[2] = fmaf(wj1, bflo(v1.y), acc[2]); acc[3] = fmaf(wj1, bfhi(v1.y), acc[3]);
            acc[4] = fmaf(wj1, bflo(v1.z), acc[4]); acc[5] = fmaf(wj1, bfhi(v1.z), acc[5]);
            acc[6] = fmaf(wj1, bflo(v1.w), acc[6]); acc[7] = fmaf(wj1, bfhi(v1.w), acc[7]);
        }
        for (; j < dlim; j += 8){
            int sj = ss2[wave][j + eg]; float wj = sw2[wave][j + eg];
            uint4 v = h2p4[(size_t)sj * 8 + cl];
            acc[0] = fmaf(wj, bflo(v.x), acc[0]); acc[1] = fmaf(wj, bfhi(v.x), acc[1]);
            acc[2] = fmaf(wj, bflo(v.y), acc[2]); acc[3] = fmaf(wj, bfhi(v.y), acc[3]);
            acc[4] = fmaf(wj, bflo(v.z), acc[4]); acc[5] = fmaf(wj, bfhi(v.z), acc[5]);
            acc[6] = fmaf(wj, bflo(v.w), acc[6]); acc[7] = fmaf(wj, bfhi(v.w), acc[7]);
        }
    } else {
        for (int base = begin; base < end; base += 64){
            int n = end - base; if (n > 64) n = 64;
            float w = 0.f; int sv = 0;
            if (lane < n){
                sv = csr[base + lane];
                float e = als[sv] + adv; e = e > 0.f ? e : NEG * e;
                w = __expf(e); wsl += w;
            }
            __threadfence_block();
            ss2[wave][lane] = sv;
            sw2[wave][lane] = w;
            __threadfence_block();
            int dlim = (n + 7) & ~7;
            for (int j = 0; j < dlim; j += 8){
                int sj = ss2[wave][j + eg]; float wj = sw2[wave][j + eg];
                uint4 v = h2p4[(size_t)sj * 8 + cl];
                acc[0] = fmaf(wj, bflo(v.x), acc[0]); acc[1] = fmaf(wj, bfhi(v.x), acc[1]);
                acc[2] = fmaf(wj, bflo(v.y), acc[2]); acc[3] = fmaf(wj, bfhi(v.y), acc[3]);
                acc[4] = fmaf(wj, bflo(v.z), acc[4]); acc[5] = fmaf(wj, bfhi(v.z), acc[5]);
                acc[6] = fmaf(wj, bflo(v.w), acc[6]); acc[7] = fmaf(wj, bfhi(v.w), acc[7]);
            }
        }
    }
    for (int o = 32; o > 0; o >>= 1) wsl += __shfl_xor(wsl, o);
    #pragma unroll
    for (int i = 0; i < 8; ++i){
        acc[i] += __shfl_xor(acc[i], 8);
        acc[i] += __shfl_xor(acc[i], 16);
        acc[i] += __shfl_xor(acc[i], 32);
    }
    if (eg == 0){                        // lanes 0..7, lane == cl
        float inv = 1.f / (wsl + 1e-16f);
        int c0 = cl * 8;
        ((float4*)out)[node * 16 + cl * 2]     = make_float4(acc[0] * inv + b2[c0],
                                                             acc[1] * inv + b2[c0 + 1],
                                                             acc[2] * inv + b2[c0 + 2],
                                                             acc[3] * inv + b2[c0 + 3]);
        ((float4*)out)[node * 16 + cl * 2 + 1] = make_float4(acc[4] * inv + b2[c0 + 4],
                                                             acc[5] * inv + b2[c0 + 5],
                                                             acc[6] * inv + b2[c0 + 6],
                                                             acc[7] * inv + b2[c0 + 7]);
    }
}

// ---------------- launch ----------------

extern "C" void kernel_launch(void* const* d_in, const int* in_sizes, int n_in,
                              void* d_out, int out_size, void* d_ws, size_t ws_size,
                              hipStream_t stream){
    const float* x   = (const float*)d_in[0];
    const int*   ei  = (const int*)d_in[1];
    const float* W1  = (const float*)d_in[2];
    const float* as1 = (const float*)d_in[3];
    const float* ad1 = (const float*)d_in[4];
    const float* b1  = (const float*)d_in[5];
    const float* W2  = (const float*)d_in[6];
    const float* as2 = (const float*)d_in[7];
    const float* ad2 = (const float*)d_in[8];
    const float* b2  = (const float*)d_in[9];
    float* out = (float*)d_out;

    char* p = (char*)d_ws;
    auto alloc = [&](size_t bytes)->void*{
        void* r = (void*)p;
        p += (bytes + 255) & ~(size_t)255;
        return r;
    };
    int*   gcur     = (int*)alloc(NBUCK * 4);
    int*   offsets  = (int*)alloc(NN * 4);
    int*   endsv    = (int*)alloc(NN * 4);
    // bdata (8.03 MB, dead after K2) aliased with helub (12.8 MB, written in edge1)
    void*  ualias   = alloc((size_t)NN * 64 * 4);
    uint*  bdata    = (uint*)ualias;
    uint*  helub    = (uint*)ualias;
    int*   csr      = (int*)alloc((size_t)ET * 4);
    uint*  h1b      = (uint*)alloc((size_t)NN * 64 * 4);
    float* als1     = (float*)alloc((size_t)NN * 4 * 4);
    float* ald1     = (float*)alloc((size_t)NN * 4 * 4);
    uint*  h2b      = (uint*)alloc((size_t)NN * 32 * 4);
    float* als2     = (float*)alloc((size_t)NN * 4);
    float* ald2     = (float*)alloc((size_t)NN * 4);
    size_t need = (size_t)(p - (char*)d_ws);   // ~41 MB

    if (ws_size < need){
        hipMemsetAsync(d_out, 0, (size_t)out_size * 4, stream);
        return;
    }

    hipMemsetAsync(gcur, 0, NBUCK * 4, stream);
    k1_kernel<<<NBLK_A + G1_SPLIT, 256, 0, stream>>>(ei, gcur, bdata,
                                                     x, W1, as1, ad1, h1b, als1, ald1);
    k2_kernel<<<NBUCK + (G1_BLOCKS - G1_SPLIT), 256, 0, stream>>>(bdata, gcur, offsets, endsv, csr,
                                                                  x, W1, as1, ad1, h1b, als1, ald1);
    edge1_kernel<<<NN / 4, 256, 0, stream>>>(offsets, endsv, csr, h1b, als1, ald1, b1, helub);
    gemm2_kernel<<<(NN + 63) / 64, 256, 0, stream>>>(helub, W2, as2, ad2, h2b, als2, ald2);
    edge2_kernel<<<NN / 4, 256, 0, stream>>>(offsets, endsv, csr, h2b, als2, ald2, b2, out);
}